// Round 2
// baseline (262.156 us; speedup 1.0000x reference)
//
#include <hip/hip_runtime.h>

// ---------------------------------------------------------------------------
// YOLO NMS post-processing for MI355X.
// Pipeline: scores (LDS-staged, 2 thr/row) + 16-way sliced histogram ->
// fused select+compact (single 1024-thr block: per-thread bucket sums ->
// scan -> bucket B; then compacts candidates bucket >= B and zeroes rank[])
// -> exact rank-by-counting -> scatter by rank (+box decode) -> PACKED
// upper-triangular 64x64 IoU bitmask (row-block w stores words w..63 only)
// -> single-wave greedy scan with a DEPTH-4 DMA ring:
//   * issue batch w+3 at iter w (4 x 32 KB LDS buffers). For w<=20 the
//     63-slot vmcnt window itself guarantees batch w retired by the time
//     batch w+3's last load issues (sum L(w+1..w+3) >= 63) -> NO wait
//     instruction, just a compiler fence. For w>=21, exact-immediate
//     `s_waitcnt vmcnt(P)` with P = loads of batches w+1..w+3 in flight.
//   * diagonal word = FIRST stored word of each packed row -> one ds_read
//     (trow[lane*stride]); no separate diag array / DMA.
//   * decisions: wave-uniform scalar chain ctz -> readlane64 -> andn2
//     (readlane64(remv,w) instead of shfl for the candidate word).
//   * kept rows' packed rows OR'd into remv via grouped-4 pipelined ds_reads.
// All IoU-relevant fp32 math uses _rn intrinsics so hipcc's default
// -ffp-contract=fast cannot fuse mul+add into fma (must match numpy fp32).
// ---------------------------------------------------------------------------

#define AS1 __attribute__((address_space(1)))
#define AS3 __attribute__((address_space(3)))

constexpr int    N_ANCH = 100800;
constexpr int    DIMV   = 117;   // 4 box + 1 obj + 80 cls + 32 mask
constexpr int    TOPKN  = 4096;
constexpr int    MAXDET = 300;
constexpr int    KCAP   = 12288; // candidate capacity
constexpr int    NBUCK  = 16384; // scores < 1.0 -> bits>>16 < 0x3F80 < 16384
constexpr int    NSLICE = 16;

// packed mask geometry: row-block w (rows [64w,64w+64)) stores words w..63
// contiguously: 64 rows x (64-w) u64. pbase64(w) = 64 * (64w - w(w-1)/2).
constexpr int PACK_TOT = 133120;                  // 64 * 2080 u64 = 1,064,960 B

// workspace layout (bytes)
constexpr size_t WS_SLICES = 0;                                   // 16*16384 u32
constexpr size_t WS_SCORES = WS_SLICES + (size_t)NSLICE * NBUCK * 4;
constexpr size_t WS_CLS    = WS_SCORES + (size_t)N_ANCH * 4;
constexpr size_t WS_SEL    = WS_CLS    + (size_t)N_ANCH * 4;      // 64 i32
constexpr size_t WS_KEYS   = WS_SEL    + 256;                     // 12288 u64
constexpr size_t WS_RANK   = WS_KEYS   + (size_t)KCAP * 8;        // 12288 i32
constexpr size_t WS_SIDX   = WS_RANK   + (size_t)KCAP * 4;        // 4096 i32
constexpr size_t WS_SSC    = WS_SIDX   + 4096ull * 4;             // 4096 f32
constexpr size_t WS_BOXES  = WS_SSC    + 4096ull * 4;             // 4096*4 f32
constexpr size_t WS_MASKP  = WS_BOXES  + 4096ull * 16;            // packed mask
constexpr size_t WS_OUTI   = WS_MASKP  + (size_t)PACK_TOT * 8 + 4096; // +DMA pad
constexpr size_t WS_OUTS   = WS_OUTI   + 1280;                    // 300 f32

__global__ void zero_kernel(unsigned* __restrict__ slices, int* __restrict__ sel) {
    int i = blockIdx.x * 256 + threadIdx.x;
    if (i < NSLICE * NBUCK) slices[i] = 0u;
    if (i < 64)             sel[i]    = 0;
}

// 64 rows per 128-thread block, staged to LDS with coalesced float4 loads.
// 2 threads per row: even lane scans classes 0..39, odd lane 40..79, merged
// via shfl_xor. Strict > keeps the first (lowest-class) argmax like numpy.
// Histogram atomics go to slice (blockIdx & 15) to spread hot-line contention.
constexpr int SROWS = 64;
__global__ void score_kernel(const float* __restrict__ x, float* __restrict__ scores,
                             int* __restrict__ cls, unsigned* __restrict__ slices) {
    __shared__ float sx[SROWS * DIMV];           // 29952 B
    int block0 = blockIdx.x * SROWS;
    const float4* src = (const float4*)(x + (size_t)block0 * DIMV); // 64*468 % 16 == 0
    float4* dst = (float4*)sx;
    constexpr int NV4 = SROWS * DIMV / 4;        // 1872
    for (int i = threadIdx.x; i < NV4; i += 128) dst[i] = src[i];
    __syncthreads();
    int row  = threadIdx.x >> 1;
    int half = threadIdx.x & 1;
    const float* rp = sx + row * DIMV;
    float obj = rp[4];
    const float* cp = rp + 5 + half * 40;
    float best = -1.0f;
    int   bc   = half * 40;
#pragma unroll 8
    for (int c = 0; c < 40; ++c) {
        float s = __fmul_rn(cp[c], obj);
        if (s > best) { best = s; bc = half * 40 + c; }
    }
    float so = __shfl_xor(best, 1);
    int   co = __shfl_xor(bc, 1);
    if (half == 0) {
        if (so > best) { best = so; bc = co; }   // strict >: even (lower classes) wins ties
        int a = block0 + row;
        bool valid = obj > 0.25f;
        scores[a] = valid ? best : -1.0f;
        cls[a]    = bc;
        if (valid) {
            unsigned b = __float_as_uint(best) >> 16;   // < 16384 (best in [0,1))
            atomicAdd(&slices[(blockIdx.x & (NSLICE - 1)) * NBUCK + b], 1u);
        }
    }
}

// fused select + compact, one 1024-thread block.
// Phase 1 (select): thread t owns 16 buckets (chunk t = [NBUCK-16(t+1),..+16),
// t=0 = top), sums them across the 16 slices into registers, scans chunk
// totals; the boundary thread walks its register copy to find bucket B with
// cntAbove(B) < 4096 <= cntAbove(B) + hist[B].
// Phase 2 (compact): all anchors with bucket >= B -> keys[]
// (key = (score_bits<<32)|~a: descending key == (score desc, idx asc) ==
// stable top_k order). Also zeroes rank[]. Writes sel[2] = n.
__global__ void select_compact_kernel(const unsigned* __restrict__ slices,
                                      const float* __restrict__ scores,
                                      int* __restrict__ sel,
                                      unsigned long long* __restrict__ keys,
                                      int* __restrict__ rank) {
    __shared__ unsigned sv[1024];
    __shared__ int selB;
    __shared__ int nctr;
    int t = threadIdx.x;
    int base = NBUCK - 16 * (t + 1);
    unsigned hb[16];
#pragma unroll
    for (int k = 0; k < 16; ++k) hb[k] = 0u;
    for (int s = 0; s < NSLICE; ++s) {
        const uint4* hp = (const uint4*)(slices + (size_t)s * NBUCK + base);
#pragma unroll
        for (int q = 0; q < 4; ++q) {
            uint4 v = hp[q];
            hb[q * 4 + 0] += v.x; hb[q * 4 + 1] += v.y;
            hb[q * 4 + 2] += v.z; hb[q * 4 + 3] += v.w;
        }
    }
    unsigned own = 0;
#pragma unroll
    for (int k = 0; k < 16; ++k) own += hb[k];
    sv[t] = own;
    if (t == 0) { selB = 0; nctr = 0; }
    __syncthreads();
    for (int off = 1; off < 1024; off <<= 1) { // inclusive scan (descending-chunk order)
        unsigned v = (t >= off) ? sv[t - off] : 0u;
        __syncthreads();
        sv[t] += v;
        __syncthreads();
    }
    unsigned incl = sv[t];
    unsigned before = incl - own;
    if (before < (unsigned)TOPKN && incl >= (unsigned)TOPKN) {
        unsigned running = before;
        for (int k = 15; k >= 0; --k) {        // walk own buckets descending
            running += hb[k];
            if (running >= (unsigned)TOPKN) { selB = base + k; break; }
        }
    }
    __syncthreads();
    int B = selB;
    for (int a = t; a < KCAP; a += 1024) rank[a] = 0;
    for (int a = t; a < N_ANCH; a += 1024) {
        float s = scores[a];
        if (s < 0.0f) continue;
        unsigned bits = __float_as_uint(s);
        if ((int)(bits >> 16) < B) continue;
        int pos = atomicAdd(&nctr, 1);
        if (pos < KCAP) keys[pos] = ((unsigned long long)bits << 32) | (unsigned)(~a);
    }
    __syncthreads();
    if (t == 0) sel[2] = (nctr > KCAP) ? KCAP : nctr;
}

// exact rank by counting: rank[i] = #{j : key_j > key_i}. Keys unique ->
// ranks are a permutation; ranks 0..4095 are the sorted top-4096.
// 8 column slabs; blocks past n exit immediately (n ~ 4.5k << KCAP).
constexpr int NCOLP = 8;
__global__ void rank_kernel(const unsigned long long* __restrict__ keys,
                            const int* __restrict__ sel, int* __restrict__ rank) {
    __shared__ unsigned long long tile[2048];
    int n = sel[2]; if (n > KCAP) n = KCAP;
    if (blockIdx.x * 256 >= n) return;           // no owning keys in this block
    int t0 = blockIdx.y * 2048;                  // 2048*8 = 16384 >= KCAP: one tile
    if (t0 >= n) return;                         // empty column slab
    int i = blockIdx.x * 256 + threadIdx.x;
    unsigned long long myKey = (i < n) ? keys[i] : 0ull;
    int m = n - t0; if (m > 2048) m = 2048;
    for (int j = threadIdx.x; j < m; j += 256) tile[j] = keys[t0 + j];
    __syncthreads();
    int cnt = 0;
    int j = 0;
    for (; j + 3 < m; j += 4) {
        cnt += (tile[j]     > myKey);
        cnt += (tile[j + 1] > myKey);
        cnt += (tile[j + 2] > myKey);
        cnt += (tile[j + 3] > myKey);
    }
    for (; j < m; ++j) cnt += (tile[j] > myKey);
    if (i < n && cnt) atomicAdd(&rank[i], cnt);
}

// place keys by rank; also decode the yxyx box for the sorted slot (no fma).
__global__ void scatter_kernel(const float* __restrict__ x,
                               const unsigned long long* __restrict__ keys,
                               const int* __restrict__ sel, const int* __restrict__ rank,
                               int* __restrict__ sidx, float* __restrict__ sscore,
                               float* __restrict__ boxes) {
    int n = sel[2]; if (n > KCAP) n = KCAP;
    int i = blockIdx.x * 256 + threadIdx.x;
    if (i >= n) return;
    int r = rank[i];
    if (r >= TOPKN) return;
    unsigned long long k = keys[i];
    int a = (int)(~(unsigned)(k & 0xFFFFFFFFull));
    sidx[r]   = a;
    sscore[r] = __uint_as_float((unsigned)(k >> 32));
    const float* p = x + (size_t)a * DIMV;
    float xc = p[0], yc = p[1], w = p[2], h = p[3];
    float hw = __fmul_rn(w, 0.5f);
    float hh = __fmul_rn(h, 0.5f);
    boxes[r * 4 + 0] = __fsub_rn(yc, hh);
    boxes[r * 4 + 1] = __fsub_rn(xc, hw);
    boxes[r * 4 + 2] = __fadd_rn(yc, hh);
    boxes[r * 4 + 3] = __fadd_rn(xc, hw);
}

// 64x64 tile IoU bitmask, PACKED upper triangle only. Row-block rowT stores
// words rowT..63: row r=64*rowT+t word colT lives at
//   maskp[pbase64(rowT) + t*(64-rowT) + (colT-rowT)].
// The diagonal block (colT==rowT) is the FIRST stored word of each row.
// Lower-triangle blocks write NOTHING.
__global__ void iou_mask_kernel(const float* __restrict__ boxes,
                                unsigned long long* __restrict__ maskp) {
    int colT = blockIdx.x, rowT = blockIdx.y;
    if (colT < rowT) return;                 // never materialized
    int t = threadIdx.x;                     // 0..63
    __shared__ float cb[64][5];
    const float4* bp = (const float4*)boxes; // y1 x1 y2 x2, 16B-aligned
    int cj = colT * 64 + t;
    {
        float4 c = bp[cj];
        cb[t][0] = c.x; cb[t][1] = c.y; cb[t][2] = c.z; cb[t][3] = c.w;
        cb[t][4] = __fmul_rn(__fsub_rn(c.z, c.x), __fsub_rn(c.w, c.y));
    }
    __syncthreads();
    int r = rowT * 64 + t;
    float4 rv = bp[r];
    float ry1 = rv.x, rx1 = rv.y, ry2 = rv.z, rx2 = rv.w;
    float rarea = __fmul_rn(__fsub_rn(ry2, ry1), __fsub_rn(rx2, rx1));
    unsigned long long bitsw = 0ull;
#pragma unroll 8
    for (int j = 0; j < 64; ++j) {
        float iy1 = fmaxf(ry1, cb[j][0]);
        float ix1 = fmaxf(rx1, cb[j][1]);
        float iy2 = fminf(ry2, cb[j][2]);
        float ix2 = fminf(rx2, cb[j][3]);
        float ih = fmaxf(__fsub_rn(iy2, iy1), 0.0f);
        float iw = fmaxf(__fsub_rn(ix2, ix1), 0.0f);
        float inter = __fmul_rn(ih, iw);
        float uni = __fsub_rn(__fadd_rn(rarea, cb[j][4]), inter);
        float iou = __fdiv_rn(inter, fmaxf(uni, 1e-9f));
        if (iou > 0.45f && (colT * 64 + j) > r) bitsw |= (1ull << j);
    }
    int pb = 64 * (64 * rowT - (rowT * (rowT - 1)) / 2);
    maskp[pb + t * (64 - rowT) + (colT - rowT)] = bitsw;
}

__device__ __forceinline__ unsigned long long readlane64(unsigned long long v, int l) {
    unsigned lo = (unsigned)__builtin_amdgcn_readlane((int)(unsigned)(v & 0xFFFFFFFFull), l);
    unsigned hi = (unsigned)__builtin_amdgcn_readlane((int)(unsigned)(v >> 32), l);
    return ((unsigned long long)hi << 32) | lo;
}

// Single-wave greedy scan over the packed mask, DEPTH-4 DMA ring.
// lane j owns remv word j. Per batch w (rows [64w,64w+64)):
//   1. issue batch w+3's DMA (L(w+3) KB-loads, monotone order, ring buf (w+3)&3)
//   2. await batch w: for w<=20, sum L(w+1..w+3) >= 63 so the 63-slot vmcnt
//      window already forced batch w to retire before batch w+3's last load
//      issued (retired >= C(w+3)-63 >= C(w)) -> compiler fence only. For
//      w>=21, `s_waitcnt vmcnt(P)` with P = sum L(w+1..w+3) (rounded down to
//      even; conservative by at most one load).
//   3. decisions from the diagonal word (first stored word of each packed
//      row, one ds_read): wave-uniform scalar chain ctz -> readlane64 -> andn2.
//   4. kept rows' packed rows OR'd into remv (grouped-4 pipelined ds_reads,
//      lanes j>=w only; words j<w are final and never re-read).
// Buffer ring: batch w -> buf w&3, written at iter w-3 (or prologue), read at
// iter w, overwritten at iter w+1's issue of batch w+4... = buf w&3 again at
// iter w+1+3-4 -> strictly after its reads. Only the final __syncthreads drains.
__global__ void __launch_bounds__(64, 1)
nms_scan_kernel(const unsigned long long* __restrict__ maskp,
                const float* __restrict__ sscore,
                int* __restrict__ outIdx, float* __restrict__ outScore) {
    int lane = threadIdx.x;              // 64 threads = one wave
    unsigned long long remv = 0ull;
    __shared__ __align__(16) unsigned long long tile[4 * 4096];   // 4 x 32 KB
    __shared__ int keepArr[MAXDET];
    __shared__ unsigned long long remvFinal[64];
    int count = 0;

    auto issueBatch = [&](int w) {
        if (w >= 64) return;
        int L = (65 - w) >> 1;           // ceil((64-w)*512B / 1024B)
        const char* gbase = (const char*)maskp +
                            (size_t)(64 * (64 * w - (w * (w - 1)) / 2)) * 8 +
                            (size_t)lane * 16;
        char* lbase = (char*)tile + (size_t)(w & 3) * 32768;
        for (int i = 0; i < L; ++i) {
            __builtin_amdgcn_global_load_lds(
                (AS1 const unsigned*)(gbase + (size_t)i * 1024),
                (AS3 unsigned*)(lbase + (size_t)i * 1024), 16, 0, 0);
        }
    };

    issueBatch(0); issueBatch(1); issueBatch(2);

#define VW(n) asm volatile("s_waitcnt vmcnt(" #n ")" ::: "memory")

    for (int w = 0; w < 64 && count < MAXDET; ++w) {
        issueBatch(w + 3);
        unsigned long long cand = ~readlane64(remv, w);   // wave-uniform
        if (!cand) continue;                              // dead batch: no wait
        int P = ((w + 1 < 64) ? ((64 - w) >> 1) : 0)      // L(w+1)
              + ((w + 2 < 64) ? ((63 - w) >> 1) : 0)      // L(w+2)
              + ((w + 3 < 64) ? ((62 - w) >> 1) : 0);     // L(w+3)
        if (P < 63) {
            switch (P >> 1) {   // VW(2k) <= P: conservative by <= 1 load
                case  0: VW(0);  break; case  1: VW(2);  break;
                case  2: VW(4);  break; case  3: VW(6);  break;
                case  4: VW(8);  break; case  5: VW(10); break;
                case  6: VW(12); break; case  7: VW(14); break;
                case  8: VW(16); break; case  9: VW(18); break;
                case 10: VW(20); break; case 11: VW(22); break;
                case 12: VW(24); break; case 13: VW(26); break;
                case 14: VW(28); break; case 15: VW(30); break;
                case 16: VW(32); break; case 17: VW(34); break;
                case 18: VW(36); break; case 19: VW(38); break;
                case 20: VW(40); break; case 21: VW(42); break;
                case 22: VW(44); break; case 23: VW(46); break;
                case 24: VW(48); break; case 25: VW(50); break;
                case 26: VW(52); break; case 27: VW(54); break;
                case 28: VW(56); break; case 29: VW(58); break;
                case 30: VW(60); break; default: VW(62); break;
            }
        } else {
            asm volatile("" ::: "memory");   // compiler-only fence (HW window covers)
        }
        const unsigned long long* trow = tile + (size_t)(w & 3) * 4096;
        int stride = 64 - w;
        // --- decisions: scalar chain on the diagonal word ------------------
        unsigned long long diagv = trow[(size_t)lane * stride]; // word w of row 64w+lane
        unsigned long long alive = cand;
        unsigned long long keptM = 0ull;
        while (alive && count < MAXDET) {
            int b = (int)__builtin_ctzll(alive);      // wave-uniform
            unsigned long long db = readlane64(diagv, b);
            if (lane == 0) keepArr[count] = (w << 6) + b;
            count++;
            keptM |= (1ull << b);
            alive &= ~(db | (1ull << b));
        }
        // --- OR kept rows' full packed rows into remv (grouped-4) ----------
        int rel = lane - w;                           // word j stored at rel >= 0
        while (keptM) {
            int bs[4]; unsigned long long t2 = keptM; int g = 0;
#pragma unroll
            for (int t = 0; t < 4; ++t) {
                bs[t] = t2 ? (int)__builtin_ctzll(t2) : 0;
                if (t2) { t2 &= t2 - 1; g = t + 1; }
            }
            unsigned long long vs[4];
#pragma unroll
            for (int t = 0; t < 4; ++t)               // independent, pipelined ds_reads
                vs[t] = (rel >= 0) ? trow[bs[t] * stride + rel] : 0ull;
#pragma unroll
            for (int t = 0; t < 4; ++t)
                if (t < g) remv |= vs[t];
            keptM = t2;
        }
    }
    __syncthreads();                      // drain outstanding DMA before output
    remvFinal[lane] = remv;
    __syncthreads();
    int K = count;                        // uniform across the wave
    for (int k = lane; k < K; k += 64) {
        int s = keepArr[k];
        outIdx[k] = s;
        outScore[k] = sscore[s];
    }
    if (K < MAXDET && lane == 0) {
        int filled = K;
        for (int w = 0; w < 64 && filled < MAXDET; ++w) {
            unsigned long long word = remvFinal[w];
            while (word && filled < MAXDET) {
                int b = (int)__builtin_ctzll(word);
                word &= word - 1;
                outIdx[filled] = (w << 6) + b;
                outScore[filled] = -1.0f;
                filled++;
            }
        }
    }
}

// emit: boxes[300*4] | classes[300] | scores[300] | masks[300*32]
__global__ void write_out_kernel(const float* __restrict__ x, const int* __restrict__ sidx,
                                 const int* __restrict__ cls, const float* __restrict__ boxes,
                                 const int* __restrict__ outIdx, const float* __restrict__ outScore,
                                 float* __restrict__ out) {
    int o = blockIdx.x;                  // 300
    int t = threadIdx.x;                 // 64
    int s = outIdx[o];
    int a = sidx[s];
    if (t < 32) {
        out[1800 + o * 32 + t] = x[(size_t)a * DIMV + 85 + t];
    } else if (t < 36) {
        out[o * 4 + (t - 32)] = boxes[s * 4 + (t - 32)];
    } else if (t == 36) {
        out[1200 + o] = (float)cls[a];
    } else if (t == 37) {
        out[1500 + o] = outScore[o];
    }
}

extern "C" void kernel_launch(void* const* d_in, const int* in_sizes, int n_in,
                              void* d_out, int out_size, void* d_ws, size_t ws_size,
                              hipStream_t stream) {
    const float* x = (const float*)d_in[0];
    char* ws = (char*)d_ws;
    unsigned*            slices = (unsigned*)(ws + WS_SLICES);
    float*               scores = (float*)(ws + WS_SCORES);
    int*                 cls    = (int*)(ws + WS_CLS);
    int*                 sel    = (int*)(ws + WS_SEL);
    unsigned long long*  keys   = (unsigned long long*)(ws + WS_KEYS);
    int*                 rank   = (int*)(ws + WS_RANK);
    int*                 sidx   = (int*)(ws + WS_SIDX);
    float*               sscore = (float*)(ws + WS_SSC);
    float*               boxes  = (float*)(ws + WS_BOXES);
    unsigned long long*  maskp  = (unsigned long long*)(ws + WS_MASKP);
    int*                 outIdx = (int*)(ws + WS_OUTI);
    float*               outSc  = (float*)(ws + WS_OUTS);

    zero_kernel<<<(NSLICE * NBUCK + 255) / 256, 256, 0, stream>>>(slices, sel);
    score_kernel<<<N_ANCH / SROWS, 128, 0, stream>>>(x, scores, cls, slices);
    select_compact_kernel<<<1, 1024, 0, stream>>>(slices, scores, sel, keys, rank);
    dim3 rg(KCAP / 256, NCOLP);
    rank_kernel<<<rg, 256, 0, stream>>>(keys, sel, rank);
    scatter_kernel<<<KCAP / 256, 256, 0, stream>>>(x, keys, sel, rank, sidx, sscore, boxes);
    dim3 mg(64, 64);
    iou_mask_kernel<<<mg, 64, 0, stream>>>(boxes, maskp);
    nms_scan_kernel<<<1, 64, 0, stream>>>(maskp, sscore, outIdx, outSc);
    write_out_kernel<<<MAXDET, 64, 0, stream>>>(x, sidx, cls, boxes, outIdx, outSc, (float*)d_out);
}

// Round 3
// 223.567 us; speedup vs baseline: 1.1726x; 1.1726x over previous
//
#include <hip/hip_runtime.h>

// ---------------------------------------------------------------------------
// YOLO NMS post-processing for MI355X.
// Pipeline: scores (LDS-staged, 2 thr/row) + 16-way sliced histogram ->
// multi-block reduce_hist -> tiny single-block select (64 KB) -> multi-block
// compact (bucket >= B, also zeroes rank[]) -> exact rank-by-counting ->
// scatter by rank (+box decode) -> PACKED upper-triangular 64x64 IoU bitmask
// (row-block w stores words w..63 only) + contiguous diag[] (in-batch 64x64
// blocks) -> single-wave greedy scan, DEPTH-4 DMA ring:
//   * diag[] (32 KB, ALL batches' decision matrices) preloaded ONCE into LDS;
//     per-batch decision reads diagLds[(w<<6)|lane] are lane-consecutive ->
//     conflict-free (the packed-row diagonal read trow[lane*stride] was a
//     32-way bank conflict at even strides -- removed from the serial path).
//   * issue batch w+3 at iter w (ring slots 32/32/31/31 KB). For the wait:
//     P = loads of batches w+1..w+3 in flight; if P >= 63 the 63-slot vmcnt
//     window already forced batch w (and diag, oldest) to retire by the time
//     batch w+3's last load issued -> compiler fence only; else exact
//     `s_waitcnt vmcnt(2*floor(P/2))`. Monotone issue order keeps this valid
//     across skipped dead batches. Only the final __syncthreads drains.
//   * decisions: wave-uniform scalar chain ctz -> readlane64 -> andn2.
//   * kept rows' packed rows OR'd into remv via grouped-4 pipelined ds_reads.
//   * keepArr aliases dead diag areas (writes < 256(w+1) B < 512(w+1) B live
//     frontier); remvFinal aliases the ring after the final drain.
// All IoU-relevant fp32 math uses _rn intrinsics so hipcc's default
// -ffp-contract=fast cannot fuse mul+add into fma (must match numpy fp32).
// ---------------------------------------------------------------------------

#define AS1 __attribute__((address_space(1)))
#define AS3 __attribute__((address_space(3)))

constexpr int    N_ANCH = 100800;
constexpr int    DIMV   = 117;   // 4 box + 1 obj + 80 cls + 32 mask
constexpr int    TOPKN  = 4096;
constexpr int    MAXDET = 300;
constexpr int    KCAP   = 12288; // candidate capacity
constexpr int    NBUCK  = 16384; // scores < 1.0 -> bits>>16 < 0x3F80 < 16384
constexpr int    NSLICE = 16;

// packed mask geometry: row-block w (rows [64w,64w+64)) stores words w..63
// contiguously: 64 rows x (64-w) u64. pbase64(w) = 64 * (64w - w(w-1)/2).
constexpr int PACK_TOT = 133120;                  // 64 * 2080 u64 = 1,064,960 B

// workspace layout (bytes)
constexpr size_t WS_HIST   = 0;                                   // 16384 u32
constexpr size_t WS_SLICES = WS_HIST   + 65536;                   // 16*16384 u32
constexpr size_t WS_SCORES = WS_SLICES + (size_t)NSLICE * NBUCK * 4;
constexpr size_t WS_CLS    = WS_SCORES + (size_t)N_ANCH * 4;
constexpr size_t WS_SEL    = WS_CLS    + (size_t)N_ANCH * 4;      // 64 i32
constexpr size_t WS_KEYS   = WS_SEL    + 256;                     // 12288 u64
constexpr size_t WS_RANK   = WS_KEYS   + (size_t)KCAP * 8;        // 12288 i32
constexpr size_t WS_SIDX   = WS_RANK   + (size_t)KCAP * 4;        // 4096 i32
constexpr size_t WS_SSC    = WS_SIDX   + 4096ull * 4;             // 4096 f32
constexpr size_t WS_BOXES  = WS_SSC    + 4096ull * 4;             // 4096*4 f32
constexpr size_t WS_MASKP  = WS_BOXES  + 4096ull * 16;            // packed mask
constexpr size_t WS_DIAG   = WS_MASKP  + (size_t)PACK_TOT * 8 + 4096; // +DMA pad
constexpr size_t WS_OUTI   = WS_DIAG   + 4096ull * 8;             // 300 i32
constexpr size_t WS_OUTS   = WS_OUTI   + 1280;                    // 300 f32

__global__ void zero_kernel(unsigned* __restrict__ slices, int* __restrict__ sel) {
    int i = blockIdx.x * 256 + threadIdx.x;
    if (i < NSLICE * NBUCK) slices[i] = 0u;
    if (i < 64)             sel[i]    = 0;
}

// 64 rows per 128-thread block, staged to LDS with coalesced float4 loads.
// 2 threads per row: even lane scans classes 0..39, odd lane 40..79, merged
// via shfl_xor. Strict > keeps the first (lowest-class) argmax like numpy.
// Histogram atomics go to slice (blockIdx & 15) to spread hot-line contention.
constexpr int SROWS = 64;
__global__ void score_kernel(const float* __restrict__ x, float* __restrict__ scores,
                             int* __restrict__ cls, unsigned* __restrict__ slices) {
    __shared__ float sx[SROWS * DIMV];           // 29952 B
    int block0 = blockIdx.x * SROWS;
    const float4* src = (const float4*)(x + (size_t)block0 * DIMV); // 64*468 % 16 == 0
    float4* dst = (float4*)sx;
    constexpr int NV4 = SROWS * DIMV / 4;        // 1872
    for (int i = threadIdx.x; i < NV4; i += 128) dst[i] = src[i];
    __syncthreads();
    int row  = threadIdx.x >> 1;
    int half = threadIdx.x & 1;
    const float* rp = sx + row * DIMV;
    float obj = rp[4];
    const float* cp = rp + 5 + half * 40;
    float best = -1.0f;
    int   bc   = half * 40;
#pragma unroll 8
    for (int c = 0; c < 40; ++c) {
        float s = __fmul_rn(cp[c], obj);
        if (s > best) { best = s; bc = half * 40 + c; }
    }
    float so = __shfl_xor(best, 1);
    int   co = __shfl_xor(bc, 1);
    if (half == 0) {
        if (so > best) { best = so; bc = co; }   // strict >: even (lower classes) wins ties
        int a = block0 + row;
        bool valid = obj > 0.25f;
        scores[a] = valid ? best : -1.0f;
        cls[a]    = bc;
        if (valid) {
            unsigned b = __float_as_uint(best) >> 16;   // < 16384 (best in [0,1))
            atomicAdd(&slices[(blockIdx.x & (NSLICE - 1)) * NBUCK + b], 1u);
        }
    }
}

// fold 16 slices into the final histogram. 64 blocks x 256 threads (GPU-wide).
__global__ void reduce_hist_kernel(const unsigned* __restrict__ slices,
                                   unsigned* __restrict__ hist) {
    int b = blockIdx.x * 256 + threadIdx.x;
    unsigned s = 0;
#pragma unroll
    for (int k = 0; k < NSLICE; ++k) s += slices[(size_t)k * NBUCK + b];
    hist[b] = s;
}

// find bucket B: cntAbove(B) < 4096 <= cntAbove(B) + hist[B]. One block,
// reads only the 64 KB hist; thread t owns 16 buckets in registers.
__global__ void select_kernel(const unsigned* __restrict__ hist, int* sel) {
    __shared__ unsigned sv[1024];
    int t = threadIdx.x;
    int base = NBUCK - 16 * (t + 1);          // chunk t covers [base, base+15], t=0 = top
    const uint4* hp = (const uint4*)(hist + base);
    unsigned hb[16];
    unsigned own = 0;
#pragma unroll
    for (int q = 0; q < 4; ++q) {
        uint4 v = hp[q];
        hb[q * 4 + 0] = v.x; hb[q * 4 + 1] = v.y;
        hb[q * 4 + 2] = v.z; hb[q * 4 + 3] = v.w;
        own += v.x + v.y + v.z + v.w;
    }
    sv[t] = own;
    __syncthreads();
    for (int off = 1; off < 1024; off <<= 1) { // inclusive scan (descending-chunk order)
        unsigned v = (t >= off) ? sv[t - off] : 0u;
        __syncthreads();
        sv[t] += v;
        __syncthreads();
    }
    unsigned incl = sv[t];
    unsigned before = incl - own;
    if (before < (unsigned)TOPKN && incl >= (unsigned)TOPKN) {
        unsigned running = before;
        for (int k = 15; k >= 0; --k) {        // walk own buckets descending
            running += hb[k];
            if (running >= (unsigned)TOPKN) {
                sel[0] = base + k;
                sel[1] = (int)(running - hb[k]);
                break;
            }
        }
    }
}

// compact all anchors with bucket >= B into keys[]; key = (score_bits<<32)|~a
// -> descending key order == (score desc, idx asc) == stable top_k order.
// Also zeroes rank[] (runs strictly before rank_kernel on the stream).
__global__ void compact_kernel(const float* __restrict__ scores, int* sel,
                               unsigned long long* __restrict__ keys,
                               int* __restrict__ rank) {
    int a = blockIdx.x * blockDim.x + threadIdx.x;
    if (a < KCAP) rank[a] = 0;
    if (a >= N_ANCH) return;
    float s = scores[a];
    if (s < 0.0f) return;
    unsigned bits = __float_as_uint(s);
    if ((int)(bits >> 16) < sel[0]) return;
    int pos = atomicAdd(&sel[2], 1);
    if (pos < KCAP) keys[pos] = ((unsigned long long)bits << 32) | (unsigned)(~a);
}

// exact rank by counting: rank[i] = #{j : key_j > key_i}. Keys unique ->
// ranks are a permutation; ranks 0..4095 are the sorted top-4096.
// 8 column slabs; blocks past n exit immediately (n ~ 4.5k << KCAP).
constexpr int NCOLP = 8;
__global__ void rank_kernel(const unsigned long long* __restrict__ keys,
                            const int* __restrict__ sel, int* __restrict__ rank) {
    __shared__ unsigned long long tile[2048];
    int n = sel[2]; if (n > KCAP) n = KCAP;
    if (blockIdx.x * 256 >= n) return;           // no owning keys in this block
    int t0 = blockIdx.y * 2048;                  // 2048*8 = 16384 >= KCAP: one tile
    if (t0 >= n) return;                         // empty column slab
    int i = blockIdx.x * 256 + threadIdx.x;
    unsigned long long myKey = (i < n) ? keys[i] : 0ull;
    int m = n - t0; if (m > 2048) m = 2048;
    for (int j = threadIdx.x; j < m; j += 256) tile[j] = keys[t0 + j];
    __syncthreads();
    int cnt = 0;
    int j = 0;
    for (; j + 3 < m; j += 4) {
        cnt += (tile[j]     > myKey);
        cnt += (tile[j + 1] > myKey);
        cnt += (tile[j + 2] > myKey);
        cnt += (tile[j + 3] > myKey);
    }
    for (; j < m; ++j) cnt += (tile[j] > myKey);
    if (i < n && cnt) atomicAdd(&rank[i], cnt);
}

// place keys by rank; also decode the yxyx box for the sorted slot (no fma).
__global__ void scatter_kernel(const float* __restrict__ x,
                               const unsigned long long* __restrict__ keys,
                               const int* __restrict__ sel, const int* __restrict__ rank,
                               int* __restrict__ sidx, float* __restrict__ sscore,
                               float* __restrict__ boxes) {
    int n = sel[2]; if (n > KCAP) n = KCAP;
    int i = blockIdx.x * 256 + threadIdx.x;
    if (i >= n) return;
    int r = rank[i];
    if (r >= TOPKN) return;
    unsigned long long k = keys[i];
    int a = (int)(~(unsigned)(k & 0xFFFFFFFFull));
    sidx[r]   = a;
    sscore[r] = __uint_as_float((unsigned)(k >> 32));
    const float* p = x + (size_t)a * DIMV;
    float xc = p[0], yc = p[1], w = p[2], h = p[3];
    float hw = __fmul_rn(w, 0.5f);
    float hh = __fmul_rn(h, 0.5f);
    boxes[r * 4 + 0] = __fsub_rn(yc, hh);
    boxes[r * 4 + 1] = __fsub_rn(xc, hw);
    boxes[r * 4 + 2] = __fadd_rn(yc, hh);
    boxes[r * 4 + 3] = __fadd_rn(xc, hw);
}

// 64x64 tile IoU bitmask, PACKED upper triangle only. Row-block rowT stores
// words rowT..63: row r=64*rowT+t word colT lives at
//   maskp[pbase64(rowT) + t*(64-rowT) + (colT-rowT)].
// Diagonal blocks additionally go to contiguous diag[rowT*64+t] (the scan's
// in-batch decision matrix). Lower-triangle blocks write NOTHING.
__global__ void iou_mask_kernel(const float* __restrict__ boxes,
                                unsigned long long* __restrict__ maskp,
                                unsigned long long* __restrict__ diag) {
    int colT = blockIdx.x, rowT = blockIdx.y;
    if (colT < rowT) return;                 // never materialized
    int t = threadIdx.x;                     // 0..63
    __shared__ float cb[64][5];
    const float4* bp = (const float4*)boxes; // y1 x1 y2 x2, 16B-aligned
    int cj = colT * 64 + t;
    {
        float4 c = bp[cj];
        cb[t][0] = c.x; cb[t][1] = c.y; cb[t][2] = c.z; cb[t][3] = c.w;
        cb[t][4] = __fmul_rn(__fsub_rn(c.z, c.x), __fsub_rn(c.w, c.y));
    }
    __syncthreads();
    int r = rowT * 64 + t;
    float4 rv = bp[r];
    float ry1 = rv.x, rx1 = rv.y, ry2 = rv.z, rx2 = rv.w;
    float rarea = __fmul_rn(__fsub_rn(ry2, ry1), __fsub_rn(rx2, rx1));
    unsigned long long bitsw = 0ull;
#pragma unroll 8
    for (int j = 0; j < 64; ++j) {
        float iy1 = fmaxf(ry1, cb[j][0]);
        float ix1 = fmaxf(rx1, cb[j][1]);
        float iy2 = fminf(ry2, cb[j][2]);
        float ix2 = fminf(rx2, cb[j][3]);
        float ih = fmaxf(__fsub_rn(iy2, iy1), 0.0f);
        float iw = fmaxf(__fsub_rn(ix2, ix1), 0.0f);
        float inter = __fmul_rn(ih, iw);
        float uni = __fsub_rn(__fadd_rn(rarea, cb[j][4]), inter);
        float iou = __fdiv_rn(inter, fmaxf(uni, 1e-9f));
        if (iou > 0.45f && (colT * 64 + j) > r) bitsw |= (1ull << j);
    }
    int pb = 64 * (64 * rowT - (rowT * (rowT - 1)) / 2);
    maskp[pb + t * (64 - rowT) + (colT - rowT)] = bitsw;
    if (colT == rowT) diag[(rowT << 6) + t] = bitsw;
}

__device__ __forceinline__ unsigned long long readlane64(unsigned long long v, int l) {
    unsigned lo = (unsigned)__builtin_amdgcn_readlane((int)(unsigned)(v & 0xFFFFFFFFull), l);
    unsigned hi = (unsigned)__builtin_amdgcn_readlane((int)(unsigned)(v >> 32), l);
    return ((unsigned long long)hi << 32) | lo;
}

// Single-wave greedy scan, DEPTH-4 ring + preloaded diag. LDS budget 158 KB:
//   ring slots (bytes): 32768, 32768, 31744, 31744  (slot k serves w==k mod 4,
//     need = L(k)*1024 where L(w)=(65-w)>>1, decreasing in w)
//   diagLds: 32768 at byte 129024. keepArr aliases diagLds (dead areas of
//     batches < w; writes reach < 256(w+1) B < 512(w+1) B frontier).
//   remvFinal aliases ring slot 0 after the final __syncthreads drain.
__global__ void __launch_bounds__(64, 1)
nms_scan_kernel(const unsigned long long* __restrict__ maskp,
                const unsigned long long* __restrict__ diagG,
                const float* __restrict__ sscore,
                int* __restrict__ outIdx, float* __restrict__ outScore) {
    int lane = threadIdx.x;              // 64 threads = one wave
    unsigned long long remv = 0ull;
    __shared__ __align__(16) unsigned long long ldsAll[20224];    // 161792 B
    constexpr int slotW[4] = {0, 4096, 8192, 12160};              // u64 offsets
    unsigned long long* diagLds = ldsAll + 16128;                 // byte 129024
    int count = 0;

    auto issueBatch = [&](int w) {
        if (w >= 64) return;
        int L = (65 - w) >> 1;           // ceil((64-w)*512B / 1024B)
        const char* gbase = (const char*)maskp +
                            (size_t)(64 * (64 * w - (w * (w - 1)) / 2)) * 8 +
                            (size_t)lane * 16;
        char* lbase = (char*)(ldsAll + slotW[w & 3]);
        for (int i = 0; i < L; ++i) {
            __builtin_amdgcn_global_load_lds(
                (AS1 const unsigned*)(gbase + (size_t)i * 1024),
                (AS3 unsigned*)(lbase + (size_t)i * 1024), 16, 0, 0);
        }
    };

    { // diag preload FIRST (oldest in queue -> retired before any batch wait)
        const char* gb = (const char*)diagG + (size_t)lane * 16;
        char* lb = (char*)diagLds;
#pragma unroll
        for (int i = 0; i < 32; ++i) {
            __builtin_amdgcn_global_load_lds(
                (AS1 const unsigned*)(gb + (size_t)i * 1024),
                (AS3 unsigned*)(lb + (size_t)i * 1024), 16, 0, 0);
        }
    }
    issueBatch(0); issueBatch(1); issueBatch(2);

#define VW(n) asm volatile("s_waitcnt vmcnt(" #n ")" ::: "memory")

    for (int w = 0; w < 64 && count < MAXDET; ++w) {
        issueBatch(w + 3);
        unsigned long long cand = ~readlane64(remv, w);   // wave-uniform
        if (!cand) continue;                              // dead batch: no wait
        int P = ((w + 1 < 64) ? ((64 - w) >> 1) : 0)      // L(w+1)
              + ((w + 2 < 64) ? ((63 - w) >> 1) : 0)      // L(w+2)
              + ((w + 3 < 64) ? ((62 - w) >> 1) : 0);     // L(w+3)
        if (P < 63) {
            switch (P >> 1) {   // VW(2k) <= P: conservative by <= 1 load
                case  0: VW(0);  break; case  1: VW(2);  break;
                case  2: VW(4);  break; case  3: VW(6);  break;
                case  4: VW(8);  break; case  5: VW(10); break;
                case  6: VW(12); break; case  7: VW(14); break;
                case  8: VW(16); break; case  9: VW(18); break;
                case 10: VW(20); break; case 11: VW(22); break;
                case 12: VW(24); break; case 13: VW(26); break;
                case 14: VW(28); break; case 15: VW(30); break;
                case 16: VW(32); break; case 17: VW(34); break;
                case 18: VW(36); break; case 19: VW(38); break;
                case 20: VW(40); break; case 21: VW(42); break;
                case 22: VW(44); break; case 23: VW(46); break;
                case 24: VW(48); break; case 25: VW(50); break;
                case 26: VW(52); break; case 27: VW(54); break;
                case 28: VW(56); break; case 29: VW(58); break;
                case 30: VW(60); break; default: VW(62); break;
            }
        } else {
            // 63-slot vmcnt window: when batch w+3's last load ISSUED, at
            // least C(w+3)-63 >= C(w) loads had retired -> batch w + diag
            // landed. Compiler fence only (no hardware wait needed).
            asm volatile("" ::: "memory");
        }
        const unsigned long long* trow = ldsAll + slotW[w & 3];
        int stride = 64 - w;
        // --- decisions: scalar chain on the preloaded, conflict-free diag --
        unsigned long long diagv = diagLds[(w << 6) | lane];
        unsigned long long alive = cand;
        unsigned long long keptM = 0ull;
        int* keepArr = (int*)diagLds;                 // aliases DEAD diag areas
        while (alive && count < MAXDET) {
            int b = (int)__builtin_ctzll(alive);      // wave-uniform
            unsigned long long db = readlane64(diagv, b);
            if (lane == 0) keepArr[count] = (w << 6) + b;
            count++;
            keptM |= (1ull << b);
            alive &= ~(db | (1ull << b));
        }
        // --- OR kept rows' full packed rows into remv (grouped-4) ----------
        int rel = lane - w;                           // word j stored at rel >= 0
        while (keptM) {
            int bs[4]; unsigned long long t2 = keptM; int g = 0;
#pragma unroll
            for (int t = 0; t < 4; ++t) {
                bs[t] = t2 ? (int)__builtin_ctzll(t2) : 0;
                if (t2) { t2 &= t2 - 1; g = t + 1; }
            }
            unsigned long long vs[4];
#pragma unroll
            for (int t = 0; t < 4; ++t)               // independent, pipelined ds_reads
                vs[t] = (rel >= 0) ? trow[bs[t] * stride + rel] : 0ull;
#pragma unroll
            for (int t = 0; t < 4; ++t)
                if (t < g) remv |= vs[t];
            keptM = t2;
        }
    }
    __syncthreads();                      // drain outstanding DMA before reuse
    unsigned long long* remvFinal = ldsAll;           // ring slot 0 (dead)
    remvFinal[lane] = remv;
    __syncthreads();
    int K = count;                        // uniform across the wave
    int* keepArr = (int*)diagLds;
    for (int k = lane; k < K; k += 64) {
        int s = keepArr[k];
        outIdx[k] = s;
        outScore[k] = sscore[s];
    }
    if (K < MAXDET && lane == 0) {
        int filled = K;
        for (int w = 0; w < 64 && filled < MAXDET; ++w) {
            unsigned long long word = remvFinal[w];
            while (word && filled < MAXDET) {
                int b = (int)__builtin_ctzll(word);
                word &= word - 1;
                outIdx[filled] = (w << 6) + b;
                outScore[filled] = -1.0f;
                filled++;
            }
        }
    }
}

// emit: boxes[300*4] | classes[300] | scores[300] | masks[300*32]
__global__ void write_out_kernel(const float* __restrict__ x, const int* __restrict__ sidx,
                                 const int* __restrict__ cls, const float* __restrict__ boxes,
                                 const int* __restrict__ outIdx, const float* __restrict__ outScore,
                                 float* __restrict__ out) {
    int o = blockIdx.x;                  // 300
    int t = threadIdx.x;                 // 64
    int s = outIdx[o];
    int a = sidx[s];
    if (t < 32) {
        out[1800 + o * 32 + t] = x[(size_t)a * DIMV + 85 + t];
    } else if (t < 36) {
        out[o * 4 + (t - 32)] = boxes[s * 4 + (t - 32)];
    } else if (t == 36) {
        out[1200 + o] = (float)cls[a];
    } else if (t == 37) {
        out[1500 + o] = outScore[o];
    }
}

extern "C" void kernel_launch(void* const* d_in, const int* in_sizes, int n_in,
                              void* d_out, int out_size, void* d_ws, size_t ws_size,
                              hipStream_t stream) {
    const float* x = (const float*)d_in[0];
    char* ws = (char*)d_ws;
    unsigned*            hist   = (unsigned*)(ws + WS_HIST);
    unsigned*            slices = (unsigned*)(ws + WS_SLICES);
    float*               scores = (float*)(ws + WS_SCORES);
    int*                 cls    = (int*)(ws + WS_CLS);
    int*                 sel    = (int*)(ws + WS_SEL);
    unsigned long long*  keys   = (unsigned long long*)(ws + WS_KEYS);
    int*                 rank   = (int*)(ws + WS_RANK);
    int*                 sidx   = (int*)(ws + WS_SIDX);
    float*               sscore = (float*)(ws + WS_SSC);
    float*               boxes  = (float*)(ws + WS_BOXES);
    unsigned long long*  maskp  = (unsigned long long*)(ws + WS_MASKP);
    unsigned long long*  diag   = (unsigned long long*)(ws + WS_DIAG);
    int*                 outIdx = (int*)(ws + WS_OUTI);
    float*               outSc  = (float*)(ws + WS_OUTS);

    zero_kernel<<<(NSLICE * NBUCK + 255) / 256, 256, 0, stream>>>(slices, sel);
    score_kernel<<<N_ANCH / SROWS, 128, 0, stream>>>(x, scores, cls, slices);
    reduce_hist_kernel<<<NBUCK / 256, 256, 0, stream>>>(slices, hist);
    select_kernel<<<1, 1024, 0, stream>>>(hist, sel);
    compact_kernel<<<(N_ANCH + 255) / 256, 256, 0, stream>>>(scores, sel, keys, rank);
    dim3 rg(KCAP / 256, NCOLP);
    rank_kernel<<<rg, 256, 0, stream>>>(keys, sel, rank);
    scatter_kernel<<<KCAP / 256, 256, 0, stream>>>(x, keys, sel, rank, sidx, sscore, boxes);
    dim3 mg(64, 64);
    iou_mask_kernel<<<mg, 64, 0, stream>>>(boxes, maskp, diag);
    nms_scan_kernel<<<1, 64, 0, stream>>>(maskp, diag, sscore, outIdx, outSc);
    write_out_kernel<<<MAXDET, 64, 0, stream>>>(x, sidx, cls, boxes, outIdx, outSc, (float*)d_out);
}

// Round 4
// 220.505 us; speedup vs baseline: 1.1889x; 1.0139x over previous
//
#include <hip/hip_runtime.h>

// ---------------------------------------------------------------------------
// YOLO NMS post-processing for MI355X.
// Pipeline: scores (LDS-staged, 2 thr/row) + 16-way sliced histogram ->
// multi-block reduce_hist -> tiny single-block select (64 KB) -> multi-block
// compact (bucket >= B, also zeroes rank[]) -> exact rank-by-counting ->
// scatter by rank (+box decode) -> PACKED upper-triangular 64x64 IoU bitmask
// (row-block w stores words w..63 only) + contiguous diag[] -> single-block
// PRODUCER-CONSUMER greedy scan (5 waves) with fused output:
//   * A single wave caps at 63 outstanding VMEM ops (~2 batches), so any
//     single-wave prefetch ring stalls INSIDE the issue loop (round-3 lesson:
//     33 of 48 us were DMA stalls). Waves 1-4 are DMA producers: producer p
//     owns batches w ≡ p (mod 4), issues that batch's global_load_lds into
//     ring slot w&3, waits vmcnt(0) (its OWN wave counter), sets ready[w].
//     Aggregate in-flight = 4x63 loads; producer stalls are off the critical
//     path. Slot reuse: consumer sets doneC[w] after its last read of slot
//     w&3; the producer of batch w+4 (the SAME wave as batch w's -> no
//     intra-slot write races) polls doneC[w]. fini flag kills producers on
//     the consumer's early exit (count==300). No __syncthreads in any loop.
//   * Consumer (wave 0) per batch is pure LDS: poll ready[w] (one ds_read in
//     steady state), conflict-free diag read diagLds[(w<<6)|lane], decision
//     chain ctz -> readlane64 -> andn2 (~25 cy/keep), grouped-8 pipelined
//     ds_reads OR kept rows into remv.
//   * diag[] (32 KB, all in-batch 64x64 decision blocks) preloaded once by
//     the consumer. keepArr aliases dead diag areas (writes < 256(w+1) B <
//     512w B live frontier; batch-w diag word is register-read before any
//     same-batch write). remvFinal aliases ring slot 0 after the final
//     barrier (producers always vmcnt(0) before flagging -> no in-flight DMA
//     at the barrier). Output (boxes/cls/score/masks) written directly by
//     all 5 waves: one fewer kernel launch.
// All IoU-relevant fp32 math uses _rn intrinsics so hipcc's default
// -ffp-contract=fast cannot fuse mul+add into fma (must match numpy fp32).
// ---------------------------------------------------------------------------

#define AS1 __attribute__((address_space(1)))
#define AS3 __attribute__((address_space(3)))

constexpr int    N_ANCH = 100800;
constexpr int    DIMV   = 117;   // 4 box + 1 obj + 80 cls + 32 mask
constexpr int    TOPKN  = 4096;
constexpr int    MAXDET = 300;
constexpr int    KCAP   = 12288; // candidate capacity
constexpr int    NBUCK  = 16384; // scores < 1.0 -> bits>>16 < 0x3F80 < 16384
constexpr int    NSLICE = 16;

// packed mask geometry: row-block w (rows [64w,64w+64)) stores words w..63
// contiguously: 64 rows x (64-w) u64. pbase64(w) = 64 * (64w - w(w-1)/2).
constexpr int PACK_TOT = 133120;                  // 64 * 2080 u64 = 1,064,960 B

// workspace layout (bytes)
constexpr size_t WS_HIST   = 0;                                   // 16384 u32
constexpr size_t WS_SLICES = WS_HIST   + 65536;                   // 16*16384 u32
constexpr size_t WS_SCORES = WS_SLICES + (size_t)NSLICE * NBUCK * 4;
constexpr size_t WS_CLS    = WS_SCORES + (size_t)N_ANCH * 4;
constexpr size_t WS_SEL    = WS_CLS    + (size_t)N_ANCH * 4;      // 64 i32
constexpr size_t WS_KEYS   = WS_SEL    + 256;                     // 12288 u64
constexpr size_t WS_RANK   = WS_KEYS   + (size_t)KCAP * 8;        // 12288 i32
constexpr size_t WS_SIDX   = WS_RANK   + (size_t)KCAP * 4;        // 4096 i32
constexpr size_t WS_SSC    = WS_SIDX   + 4096ull * 4;             // 4096 f32
constexpr size_t WS_BOXES  = WS_SSC    + 4096ull * 4;             // 4096*4 f32
constexpr size_t WS_MASKP  = WS_BOXES  + 4096ull * 16;            // packed mask
constexpr size_t WS_DIAG   = WS_MASKP  + (size_t)PACK_TOT * 8 + 4096; // +DMA pad

__global__ void zero_kernel(unsigned* __restrict__ slices, int* __restrict__ sel) {
    int i = blockIdx.x * 256 + threadIdx.x;
    if (i < NSLICE * NBUCK) slices[i] = 0u;
    if (i < 64)             sel[i]    = 0;
}

// 64 rows per 128-thread block, staged to LDS with coalesced float4 loads.
// 2 threads per row: even lane scans classes 0..39, odd lane 40..79, merged
// via shfl_xor. Strict > keeps the first (lowest-class) argmax like numpy.
// Histogram atomics go to slice (blockIdx & 15) to spread hot-line contention.
constexpr int SROWS = 64;
__global__ void score_kernel(const float* __restrict__ x, float* __restrict__ scores,
                             int* __restrict__ cls, unsigned* __restrict__ slices) {
    __shared__ float sx[SROWS * DIMV];           // 29952 B
    int block0 = blockIdx.x * SROWS;
    const float4* src = (const float4*)(x + (size_t)block0 * DIMV); // 64*468 % 16 == 0
    float4* dst = (float4*)sx;
    constexpr int NV4 = SROWS * DIMV / 4;        // 1872
    for (int i = threadIdx.x; i < NV4; i += 128) dst[i] = src[i];
    __syncthreads();
    int row  = threadIdx.x >> 1;
    int half = threadIdx.x & 1;
    const float* rp = sx + row * DIMV;
    float obj = rp[4];
    const float* cp = rp + 5 + half * 40;
    float best = -1.0f;
    int   bc   = half * 40;
#pragma unroll 8
    for (int c = 0; c < 40; ++c) {
        float s = __fmul_rn(cp[c], obj);
        if (s > best) { best = s; bc = half * 40 + c; }
    }
    float so = __shfl_xor(best, 1);
    int   co = __shfl_xor(bc, 1);
    if (half == 0) {
        if (so > best) { best = so; bc = co; }   // strict >: even (lower classes) wins ties
        int a = block0 + row;
        bool valid = obj > 0.25f;
        scores[a] = valid ? best : -1.0f;
        cls[a]    = bc;
        if (valid) {
            unsigned b = __float_as_uint(best) >> 16;   // < 16384 (best in [0,1))
            atomicAdd(&slices[(blockIdx.x & (NSLICE - 1)) * NBUCK + b], 1u);
        }
    }
}

// fold 16 slices into the final histogram. 64 blocks x 256 threads (GPU-wide).
__global__ void reduce_hist_kernel(const unsigned* __restrict__ slices,
                                   unsigned* __restrict__ hist) {
    int b = blockIdx.x * 256 + threadIdx.x;
    unsigned s = 0;
#pragma unroll
    for (int k = 0; k < NSLICE; ++k) s += slices[(size_t)k * NBUCK + b];
    hist[b] = s;
}

// find bucket B: cntAbove(B) < 4096 <= cntAbove(B) + hist[B]. One block,
// reads only the 64 KB hist; thread t owns 16 buckets in registers.
__global__ void select_kernel(const unsigned* __restrict__ hist, int* sel) {
    __shared__ unsigned sv[1024];
    int t = threadIdx.x;
    int base = NBUCK - 16 * (t + 1);          // chunk t covers [base, base+15], t=0 = top
    const uint4* hp = (const uint4*)(hist + base);
    unsigned hb[16];
    unsigned own = 0;
#pragma unroll
    for (int q = 0; q < 4; ++q) {
        uint4 v = hp[q];
        hb[q * 4 + 0] = v.x; hb[q * 4 + 1] = v.y;
        hb[q * 4 + 2] = v.z; hb[q * 4 + 3] = v.w;
        own += v.x + v.y + v.z + v.w;
    }
    sv[t] = own;
    __syncthreads();
    for (int off = 1; off < 1024; off <<= 1) { // inclusive scan (descending-chunk order)
        unsigned v = (t >= off) ? sv[t - off] : 0u;
        __syncthreads();
        sv[t] += v;
        __syncthreads();
    }
    unsigned incl = sv[t];
    unsigned before = incl - own;
    if (before < (unsigned)TOPKN && incl >= (unsigned)TOPKN) {
        unsigned running = before;
        for (int k = 15; k >= 0; --k) {        // walk own buckets descending
            running += hb[k];
            if (running >= (unsigned)TOPKN) {
                sel[0] = base + k;
                sel[1] = (int)(running - hb[k]);
                break;
            }
        }
    }
}

// compact all anchors with bucket >= B into keys[]; key = (score_bits<<32)|~a
// -> descending key order == (score desc, idx asc) == stable top_k order.
// Also zeroes rank[] (runs strictly before rank_kernel on the stream).
__global__ void compact_kernel(const float* __restrict__ scores, int* sel,
                               unsigned long long* __restrict__ keys,
                               int* __restrict__ rank) {
    int a = blockIdx.x * blockDim.x + threadIdx.x;
    if (a < KCAP) rank[a] = 0;
    if (a >= N_ANCH) return;
    float s = scores[a];
    if (s < 0.0f) return;
    unsigned bits = __float_as_uint(s);
    if ((int)(bits >> 16) < sel[0]) return;
    int pos = atomicAdd(&sel[2], 1);
    if (pos < KCAP) keys[pos] = ((unsigned long long)bits << 32) | (unsigned)(~a);
}

// exact rank by counting: rank[i] = #{j : key_j > key_i}. Keys unique ->
// ranks are a permutation; ranks 0..4095 are the sorted top-4096.
// 8 column slabs; blocks past n exit immediately (n ~ 4.5k << KCAP).
constexpr int NCOLP = 8;
__global__ void rank_kernel(const unsigned long long* __restrict__ keys,
                            const int* __restrict__ sel, int* __restrict__ rank) {
    __shared__ unsigned long long tile[2048];
    int n = sel[2]; if (n > KCAP) n = KCAP;
    if (blockIdx.x * 256 >= n) return;           // no owning keys in this block
    int t0 = blockIdx.y * 2048;                  // 2048*8 = 16384 >= KCAP: one tile
    if (t0 >= n) return;                         // empty column slab
    int i = blockIdx.x * 256 + threadIdx.x;
    unsigned long long myKey = (i < n) ? keys[i] : 0ull;
    int m = n - t0; if (m > 2048) m = 2048;
    for (int j = threadIdx.x; j < m; j += 256) tile[j] = keys[t0 + j];
    __syncthreads();
    int cnt = 0;
    int j = 0;
    for (; j + 3 < m; j += 4) {
        cnt += (tile[j]     > myKey);
        cnt += (tile[j + 1] > myKey);
        cnt += (tile[j + 2] > myKey);
        cnt += (tile[j + 3] > myKey);
    }
    for (; j < m; ++j) cnt += (tile[j] > myKey);
    if (i < n && cnt) atomicAdd(&rank[i], cnt);
}

// place keys by rank; also decode the yxyx box for the sorted slot (no fma).
__global__ void scatter_kernel(const float* __restrict__ x,
                               const unsigned long long* __restrict__ keys,
                               const int* __restrict__ sel, const int* __restrict__ rank,
                               int* __restrict__ sidx, float* __restrict__ sscore,
                               float* __restrict__ boxes) {
    int n = sel[2]; if (n > KCAP) n = KCAP;
    int i = blockIdx.x * 256 + threadIdx.x;
    if (i >= n) return;
    int r = rank[i];
    if (r >= TOPKN) return;
    unsigned long long k = keys[i];
    int a = (int)(~(unsigned)(k & 0xFFFFFFFFull));
    sidx[r]   = a;
    sscore[r] = __uint_as_float((unsigned)(k >> 32));
    const float* p = x + (size_t)a * DIMV;
    float xc = p[0], yc = p[1], w = p[2], h = p[3];
    float hw = __fmul_rn(w, 0.5f);
    float hh = __fmul_rn(h, 0.5f);
    boxes[r * 4 + 0] = __fsub_rn(yc, hh);
    boxes[r * 4 + 1] = __fsub_rn(xc, hw);
    boxes[r * 4 + 2] = __fadd_rn(yc, hh);
    boxes[r * 4 + 3] = __fadd_rn(xc, hw);
}

// 64x64 tile IoU bitmask, PACKED upper triangle only. Row-block rowT stores
// words rowT..63: row r=64*rowT+t word colT lives at
//   maskp[pbase64(rowT) + t*(64-rowT) + (colT-rowT)].
// Diagonal blocks additionally go to contiguous diag[rowT*64+t] (the scan's
// in-batch decision matrix). Lower-triangle blocks write NOTHING.
__global__ void iou_mask_kernel(const float* __restrict__ boxes,
                                unsigned long long* __restrict__ maskp,
                                unsigned long long* __restrict__ diag) {
    int colT = blockIdx.x, rowT = blockIdx.y;
    if (colT < rowT) return;                 // never materialized
    int t = threadIdx.x;                     // 0..63
    __shared__ float cb[64][5];
    const float4* bp = (const float4*)boxes; // y1 x1 y2 x2, 16B-aligned
    int cj = colT * 64 + t;
    {
        float4 c = bp[cj];
        cb[t][0] = c.x; cb[t][1] = c.y; cb[t][2] = c.z; cb[t][3] = c.w;
        cb[t][4] = __fmul_rn(__fsub_rn(c.z, c.x), __fsub_rn(c.w, c.y));
    }
    __syncthreads();
    int r = rowT * 64 + t;
    float4 rv = bp[r];
    float ry1 = rv.x, rx1 = rv.y, ry2 = rv.z, rx2 = rv.w;
    float rarea = __fmul_rn(__fsub_rn(ry2, ry1), __fsub_rn(rx2, rx1));
    unsigned long long bitsw = 0ull;
#pragma unroll 8
    for (int j = 0; j < 64; ++j) {
        float iy1 = fmaxf(ry1, cb[j][0]);
        float ix1 = fmaxf(rx1, cb[j][1]);
        float iy2 = fminf(ry2, cb[j][2]);
        float ix2 = fminf(rx2, cb[j][3]);
        float ih = fmaxf(__fsub_rn(iy2, iy1), 0.0f);
        float iw = fmaxf(__fsub_rn(ix2, ix1), 0.0f);
        float inter = __fmul_rn(ih, iw);
        float uni = __fsub_rn(__fadd_rn(rarea, cb[j][4]), inter);
        float iou = __fdiv_rn(inter, fmaxf(uni, 1e-9f));
        if (iou > 0.45f && (colT * 64 + j) > r) bitsw |= (1ull << j);
    }
    int pb = 64 * (64 * rowT - (rowT * (rowT - 1)) / 2);
    maskp[pb + t * (64 - rowT) + (colT - rowT)] = bitsw;
    if (colT == rowT) diag[(rowT << 6) + t] = bitsw;
}

__device__ __forceinline__ unsigned long long readlane64(unsigned long long v, int l) {
    unsigned lo = (unsigned)__builtin_amdgcn_readlane((int)(unsigned)(v & 0xFFFFFFFFull), l);
    unsigned hi = (unsigned)__builtin_amdgcn_readlane((int)(unsigned)(v >> 32), l);
    return ((unsigned long long)hi << 32) | lo;
}

#define VW0() asm volatile("s_waitcnt vmcnt(0)" ::: "memory")

// Producer-consumer greedy scan + fused output. 5 waves (320 threads):
//   wave 0 = consumer (decisions + remv ORs + output orchestration)
//   waves 1-4 = producers: wave 1+p owns batches w ≡ p (mod 4) -> ring slot
//   w&3 (sizes 32/32/31/31 KB). LDS: ring 126 KB + diag 32 KB + flags.
__global__ void __launch_bounds__(320, 1)
nms_scan_kernel(const unsigned long long* __restrict__ maskp,
                const unsigned long long* __restrict__ diagG,
                const float* __restrict__ sscore,
                const float* __restrict__ x,
                const int* __restrict__ sidx,
                const int* __restrict__ cls,
                const float* __restrict__ boxes,
                float* __restrict__ out) {
    __shared__ __align__(16) unsigned long long ldsAll[16128];   // ring, 129024 B
    __shared__ __align__(16) unsigned long long diagLds[4096];   // 32768 B
    __shared__ int ready[64];
    __shared__ int doneC[64];
    __shared__ int finiF;
    __shared__ int KK;
    constexpr int slotW[4] = {0, 4096, 8192, 12160};             // u64 offsets

    int wave = threadIdx.x >> 6;         // 0..4
    int lane = threadIdx.x & 63;

    if (threadIdx.x < 64) { ready[threadIdx.x] = 0; doneC[threadIdx.x] = 0; }
    if (threadIdx.x == 0) { finiF = 0; KK = 0; }
    __syncthreads();

    unsigned long long remv = 0ull;
    int count = 0;

    if (wave == 0) {
        // ---- consumer ----------------------------------------------------
        { // diag preload (own wave's vmcnt only)
            const char* gb = (const char*)diagG + (size_t)lane * 16;
            char* lb = (char*)diagLds;
#pragma unroll
            for (int i = 0; i < 32; ++i) {
                __builtin_amdgcn_global_load_lds(
                    (AS1 const unsigned*)(gb + (size_t)i * 1024),
                    (AS3 unsigned*)(lb + (size_t)i * 1024), 16, 0, 0);
            }
            VW0();
            asm volatile("" ::: "memory");
        }
        int* keepArrL = (int*)diagLds;   // aliases DEAD diag areas (see header)
        for (int w = 0; w < 64 && count < MAXDET; ++w) {
            unsigned long long cand = ~readlane64(remv, w);   // wave-uniform
            if (!cand) {                  // dead batch: no data needed
                if (lane == 0) doneC[w] = 1;
                continue;
            }
            unsigned long long diagv = diagLds[(w << 6) | lane]; // overlaps poll
            {
                volatile int* rf = &ready[w];
                while (*rf == 0) {}
            }
            asm volatile("" ::: "memory");
            const unsigned long long* trow = ldsAll + slotW[w & 3];
            int stride = 64 - w;
            // decisions: wave-uniform scalar chain on the diag block
            unsigned long long alive = cand;
            unsigned long long keptM = 0ull;
            while (alive && count < MAXDET) {
                int b = (int)__builtin_ctzll(alive);      // wave-uniform
                unsigned long long db = readlane64(diagv, b);
                if (lane == 0) keepArrL[count] = (w << 6) + b;
                count++;
                keptM |= (1ull << b);
                alive &= ~(db | (1ull << b));
            }
            // OR kept rows' packed rows into remv (grouped-8 pipelined ds_reads)
            int rel = lane - w;                           // word j stored at rel >= 0
            while (keptM) {
                int bs[8]; unsigned long long t2 = keptM; int g = 0;
#pragma unroll
                for (int t = 0; t < 8; ++t) {
                    bs[t] = t2 ? (int)__builtin_ctzll(t2) : 0;
                    if (t2) { t2 &= t2 - 1; g = t + 1; }
                }
                unsigned long long vs[8];
#pragma unroll
                for (int t = 0; t < 8; ++t)               // independent ds_reads
                    vs[t] = (rel >= 0) ? trow[bs[t] * stride + rel] : 0ull;
#pragma unroll
                for (int t = 0; t < 8; ++t)
                    if (t < g) remv |= vs[t];
                keptM = t2;
            }
            asm volatile("" ::: "memory");   // reads of slot w&3 issued before flag
            if (lane == 0) doneC[w] = 1;
        }
        asm volatile("" ::: "memory");
        if (lane == 0) finiF = 1;            // release any blocked producer
    } else {
        // ---- producers ---------------------------------------------------
        int p = wave - 1;                    // 0..3: batches w ≡ p (mod 4)
        for (int w = p; w < 64; w += 4) {
            if (w >= 4) {                    // wait for slot w&3 to be free
                volatile int* dc = &doneC[w - 4];
                volatile int* ff = &finiF;
                bool fin = false;
                for (;;) {
                    if (*dc) break;
                    if (*ff) { fin = true; break; }
                }
                if (fin) break;
            }
            int L = (65 - w) >> 1;           // ceil((64-w)*512B / 1024B)
            const char* gbase = (const char*)maskp +
                                (size_t)(64 * (64 * w - (w * (w - 1)) / 2)) * 8 +
                                (size_t)lane * 16;
            char* lbase = (char*)(ldsAll + slotW[w & 3]);
            for (int i = 0; i < L; ++i) {
                __builtin_amdgcn_global_load_lds(
                    (AS1 const unsigned*)(gbase + (size_t)i * 1024),
                    (AS3 unsigned*)(lbase + (size_t)i * 1024), 16, 0, 0);
            }
            VW0();                           // own wave's loads only
            asm volatile("" ::: "memory");
            if (lane == 0) ready[w] = 1;
        }
    }

    __syncthreads();   // (A) all DMA drained (producers vmcnt(0) before flags)

    unsigned long long* remvF = ldsAll;      // alias ring slot 0 (dead)
    if (wave == 0) {
        remvF[lane] = remv;
        if (lane == 0) KK = count;
    }
    __syncthreads();   // (B)

    int K = KK;
    int* keepArrL = (int*)diagLds;                   // [0, 1200) B
    int* sArr     = (int*)diagLds + 384;             // [1536, 2736) B
    float* scArr  = (float*)diagLds + 768;           // [3072, 4272) B
    for (int o = threadIdx.x; o < K; o += 320) {
        int s = keepArrL[o];
        sArr[o]  = s;
        scArr[o] = sscore[s];
    }
    if (threadIdx.x == 0 && K < MAXDET) {
        // fillers: suppressed rows in ascending sorted-slot order, score -1
        int filled = K;
        for (int w2 = 0; w2 < 64 && filled < MAXDET; ++w2) {
            unsigned long long word = remvF[w2];
            while (word && filled < MAXDET) {
                int b = (int)__builtin_ctzll(word);
                word &= word - 1;
                sArr[filled]  = (w2 << 6) + b;
                scArr[filled] = -1.0f;
                filled++;
            }
        }
    }
    __syncthreads();   // (C)

    // emit: boxes[300*4] | classes[300] | scores[300] | masks[300*32]
    for (int o = threadIdx.x; o < MAXDET; o += 320) {
        int s = sArr[o];
        int a = sidx[s];
        out[o * 4 + 0] = boxes[s * 4 + 0];
        out[o * 4 + 1] = boxes[s * 4 + 1];
        out[o * 4 + 2] = boxes[s * 4 + 2];
        out[o * 4 + 3] = boxes[s * 4 + 3];
        out[1200 + o] = (float)cls[a];
        out[1500 + o] = scArr[o];
        const float* mp = x + (size_t)a * DIMV + 85;
#pragma unroll
        for (int k = 0; k < 32; ++k) out[1800 + o * 32 + k] = mp[k];
    }
}

extern "C" void kernel_launch(void* const* d_in, const int* in_sizes, int n_in,
                              void* d_out, int out_size, void* d_ws, size_t ws_size,
                              hipStream_t stream) {
    const float* x = (const float*)d_in[0];
    char* ws = (char*)d_ws;
    unsigned*            hist   = (unsigned*)(ws + WS_HIST);
    unsigned*            slices = (unsigned*)(ws + WS_SLICES);
    float*               scores = (float*)(ws + WS_SCORES);
    int*                 cls    = (int*)(ws + WS_CLS);
    int*                 sel    = (int*)(ws + WS_SEL);
    unsigned long long*  keys   = (unsigned long long*)(ws + WS_KEYS);
    int*                 rank   = (int*)(ws + WS_RANK);
    int*                 sidx   = (int*)(ws + WS_SIDX);
    float*               sscore = (float*)(ws + WS_SSC);
    float*               boxes  = (float*)(ws + WS_BOXES);
    unsigned long long*  maskp  = (unsigned long long*)(ws + WS_MASKP);
    unsigned long long*  diag   = (unsigned long long*)(ws + WS_DIAG);

    zero_kernel<<<(NSLICE * NBUCK + 255) / 256, 256, 0, stream>>>(slices, sel);
    score_kernel<<<N_ANCH / SROWS, 128, 0, stream>>>(x, scores, cls, slices);
    reduce_hist_kernel<<<NBUCK / 256, 256, 0, stream>>>(slices, hist);
    select_kernel<<<1, 1024, 0, stream>>>(hist, sel);
    compact_kernel<<<(N_ANCH + 255) / 256, 256, 0, stream>>>(scores, sel, keys, rank);
    dim3 rg(KCAP / 256, NCOLP);
    rank_kernel<<<rg, 256, 0, stream>>>(keys, sel, rank);
    scatter_kernel<<<KCAP / 256, 256, 0, stream>>>(x, keys, sel, rank, sidx, sscore, boxes);
    dim3 mg(64, 64);
    iou_mask_kernel<<<mg, 64, 0, stream>>>(boxes, maskp, diag);
    nms_scan_kernel<<<1, 320, 0, stream>>>(maskp, diag, sscore, x, sidx, cls, boxes,
                                           (float*)d_out);
}